// Round 1
// 245.496 us; speedup vs baseline: 1.0012x; 1.0012x over previous
//
#include <hip/hip_runtime.h>

// PCEN: M[0]=x[0]; M[t]=(1-s)M[t-1]+s*x[t]; out=(x/(M+eps)^a + d)^r - d^r
// x, out: (64, 4000, 128) fp32.
//
// R5: same exact blocked-scan algebra as R4 (2 kernels, 1 MB partials, exact
// carry via A_C = 0.975^125), but vectorized to float2 per lane:
//  - each 64-lane wave owns a full 512 B feature row per load (8 B/lane),
//    halving VMEM instruction count vs the 4 B/lane dword version;
//  - each thread runs TWO independent scan FMA chains (features 2*lane,
//    2*lane+1), doubling ILP on the dependent path;
//  - block = 256 threads = 4 waves = 4 chunks; grid (64,8); 25-deep prefetch.
// Per-(b,f) FMA order is unchanged -> bit-identical output to R4.

typedef float v2f __attribute__((ext_vector_type(2)));

#define B_DIM 64
#define T_DIM 4000
#define F_DIM 128
#define F2    (F_DIM / 2)     // row stride in float2 units
#define NCHUNK 32
#define CLEN 125              // NCHUNK*CLEN == T_DIM
#define PF 25                 // prefetch depth; CLEN = 5*PF
#define NG (CLEN / PF)        // 5 groups
#define WPB 4                 // waves (= chunks) per block
#define A_C 0.04222576f       // 0.975^125, computed in double, rounded to fp32

__device__ __forceinline__ float pcen_out(float xv, float M) {
    const float EPS = 1e-6f, NALPHA = -0.98f, DELTA = 2.0f, SQRTD = 1.41421356237f;
    float p = __builtin_amdgcn_exp2f(NALPHA * __builtin_amdgcn_logf(M + EPS));
    return __builtin_sqrtf(__builtin_fmaf(xv, p, DELTA)) - SQRTD;
}

// ---- K1: chunk partials ----------------------------------------------------
__global__ __launch_bounds__(256) void pcen_partial(const float* __restrict__ x,
                                                    float* __restrict__ bend) {
    const float S = 0.025f, OMS = 0.975f;
    const int lane = threadIdx.x & 63;                    // float2 lane = 2 features
    const int ck   = blockIdx.y * WPB + (threadIdx.x >> 6);
    const int b    = blockIdx.x;
    const int t0   = ck * CLEN;
    const v2f* xb = (const v2f*)(x + (size_t)b * T_DIM * F_DIM) + lane;
    const float first = (ck == 0) ? 1.0f : S;             // exact M[0]=x[0] rule

    v2f buf[PF];
    #pragma unroll
    for (int u = 0; u < PF; ++u) buf[u] = xb[(t0 + u) * F2];

    float Mx = 0.0f, My = 0.0f;
    #pragma unroll
    for (int g = 0; g < NG; ++g) {
        #pragma unroll
        for (int u = 0; u < PF; ++u) {
            const int s = g * PF + u;
            const v2f xv = buf[u];
            const float ms = (s == 0) ? first : S;
            Mx = __builtin_fmaf(OMS, Mx, ms * xv.x);
            My = __builtin_fmaf(OMS, My, ms * xv.y);
            if (g + 1 < NG) buf[u] = xb[(t0 + s + PF) * F2];
        }
    }
    v2f* be = (v2f*)(bend + ((size_t)b * NCHUNK + ck) * F_DIM) + lane;
    *be = (v2f){Mx, My};                                  // chunk-end partial
}

// ---- K2: exact carry + emit ------------------------------------------------
__global__ __launch_bounds__(256) void pcen_emit(const float* __restrict__ x,
                                                 const float* __restrict__ bend,
                                                 float* __restrict__ out) {
    const float S = 0.025f, OMS = 0.975f;
    const int lane = threadIdx.x & 63;
    const int ck   = blockIdx.y * WPB + (threadIdx.x >> 6);
    const int b    = blockIdx.x;
    const int t0   = ck * CLEN;
    const v2f* xb = (const v2f*)(x   + (size_t)b * T_DIM * F_DIM) + lane;
    v2f*       ob = (v2f*)      (out + (size_t)b * T_DIM * F_DIM) + lane;
    const float first = (ck == 0) ? 1.0f : S;

    // Issue main-loop prefetches first so they overlap the carry combine.
    v2f buf[PF];
    #pragma unroll
    for (int u = 0; u < PF; ++u) buf[u] = xb[(t0 + u) * F2];

    // Exact carry-in: M_in = M_end[ck-1] from the 1 MB partials (L2-hot).
    float Mx = 0.0f, My = 0.0f;
    if (ck > 0) {
        const v2f* wb = (const v2f*)(bend + (size_t)b * NCHUNK * F_DIM) + lane;
        v2f c = wb[0];
        float cx = c.x, cy = c.y;
        #pragma unroll 8
        for (int j = 1; j < ck; ++j) {
            const v2f w = wb[j * F2];
            cx = __builtin_fmaf(A_C, cx, w.x);
            cy = __builtin_fmaf(A_C, cy, w.y);
        }
        Mx = cx; My = cy;
    }

    #pragma unroll
    for (int g = 0; g < NG; ++g) {
        #pragma unroll
        for (int u = 0; u < PF; ++u) {
            const int s = g * PF + u;
            const v2f xv = buf[u];
            const float ms = (s == 0) ? first : S;
            Mx = __builtin_fmaf(OMS, Mx, ms * xv.x);
            My = __builtin_fmaf(OMS, My, ms * xv.y);
            if (g + 1 < NG) buf[u] = xb[(t0 + s + PF) * F2];
            v2f o;
            o.x = pcen_out(xv.x, Mx);
            o.y = pcen_out(xv.y, My);
            // nontemporal: out is never re-read; keep x resident in L3
            __builtin_nontemporal_store(o, &ob[(t0 + s) * F2]);
        }
    }
}

extern "C" void kernel_launch(void* const* d_in, const int* in_sizes, int n_in,
                              void* d_out, int out_size, void* d_ws, size_t ws_size,
                              hipStream_t stream) {
    const float* x = (const float*)d_in[0];
    float* out  = (float*)d_out;
    float* bend = (float*)d_ws;   // 64*32*128 floats = 1 MB
    dim3 grid(B_DIM, NCHUNK / WPB);
    pcen_partial<<<grid, 64 * WPB, 0, stream>>>(x, bend);
    pcen_emit   <<<grid, 64 * WPB, 0, stream>>>(x, bend, out);
}